// Round 2
// baseline (13214.247 us; speedup 1.0000x reference)
//
#include <hip/hip_runtime.h>

#define NN   6144
#define EE   98304
#define DIN  128
#define DD   256
#define TT   32
#define NH   4
#define DHH  64

// ---------------- scatter-mean aggregation ----------------
// one wave per edge; feature strided across 64 lanes
__global__ void aml_scatter_k(const float* __restrict__ x,
                              const int* __restrict__ ei,
                              float* __restrict__ agg, float* __restrict__ cnt) {
    int e = blockIdx.x * 4 + (threadIdx.x >> 6);
    int lane = threadIdx.x & 63;
    if (e >= EE) return;
    int src = ei[e];
    int dst = ei[EE + e];
    #pragma unroll
    for (int f = lane; f < DIN; f += 64) {
        atomicAdd(&agg[(size_t)dst * DIN + f], x[(size_t)src * DIN + f]);
    }
    if (lane == 0) atomicAdd(&cnt[dst], 1.0f);
}

// ---------------- SAGE linear: h = lin_l(agg/cnt) + b + lin_r(x) ----------------
__global__ void aml_sage_k(const float* __restrict__ x,
                           const float* __restrict__ agg, const float* __restrict__ cnt,
                           const float* __restrict__ wl,
                           const float* __restrict__ bl,
                           const float* __restrict__ wr,
                           float* __restrict__ h) {
    int i = blockIdx.x;
    int d = threadIdx.x;  // 256
    __shared__ float xa[DIN], xs[DIN];
    if (d < DIN) {
        float inv = 1.0f / fmaxf(cnt[i], 1.0f);
        xa[d] = agg[(size_t)i * DIN + d] * inv;
        xs[d] = x[(size_t)i * DIN + d];
    }
    __syncthreads();
    float acc = bl[d];
    const float* wlr = wl + (size_t)d * DIN;
    const float* wrr = wr + (size_t)d * DIN;
    #pragma unroll 4
    for (int k = 0; k < DIN; ++k)
        acc += xa[k] * wlr[k] + xs[k] * wrr[k];
    h[(size_t)i * DD + d] = acc;
}

// ---------------- BatchNorm column stats ----------------
__global__ void aml_bn_stats_k(const float* __restrict__ h, float* __restrict__ stats) {
    int d = blockIdx.x;   // column
    int t = threadIdx.x;  // 256
    float s = 0.f, ss = 0.f;
    for (int i = t; i < NN; i += 256) {
        float v = h[(size_t)i * DD + d];
        s += v; ss += v * v;
    }
    __shared__ float rs[256], rss[256];
    rs[t] = s; rss[t] = ss;
    __syncthreads();
    for (int o = 128; o > 0; o >>= 1) {
        if (t < o) { rs[t] += rs[t + o]; rss[t] += rss[t + o]; }
        __syncthreads();
    }
    if (t == 0) {
        float mu = rs[0] / NN;
        float var = rss[0] / NN - mu * mu;
        stats[d] = mu;
        stats[DD + d] = rsqrtf(var + 1e-5f);
    }
}

__global__ void aml_bn_apply_k(float* __restrict__ h, const float* __restrict__ stats,
                               const float* __restrict__ g,
                               const float* __restrict__ b) {
    int idx = blockIdx.x * 256 + threadIdx.x;
    if (idx >= NN * DD) return;
    int d = idx & (DD - 1);
    float v = (h[idx] - stats[d]) * stats[DD + d] * g[d] + b[d];
    h[idx] = fmaxf(v, 0.0f);
}

// ---------------- timestep segment offsets (timesteps sorted) ----------------
__global__ void aml_offsets_k(const int* __restrict__ ts, int* __restrict__ offs) {
    int t = threadIdx.x;
    if (t > TT) return;
    int lo = 0, hi = NN;
    while (lo < hi) {
        int mid = (lo + hi) >> 1;
        if (ts[mid] < t) lo = mid + 1; else hi = mid;
    }
    offs[t] = lo;
}

// ---------------- generic linear: out[i,c] = dot(in[i,:K], w[c,:K]) + b[c] ----------------
template <int RELU>
__global__ void aml_lin_k(const float* __restrict__ in, const float* __restrict__ w,
                          const float* __restrict__ b, float* __restrict__ out,
                          int K, int M) {
    int i = blockIdx.x;
    int c = blockIdx.y * 256 + threadIdx.x;
    extern __shared__ float sh[];
    for (int k = threadIdx.x; k < K; k += 256) sh[k] = in[(size_t)i * K + k];
    __syncthreads();
    float acc = b[c];
    const float* wr = w + (size_t)c * K;
    #pragma unroll 4
    for (int k = 0; k < K; ++k) acc += sh[k] * wr[k];
    if (RELU) acc = fmaxf(acc, 0.0f);
    out[(size_t)i * M + c] = acc;
}

// ---------------- block-diagonal attention: one wg per (timestep, head), one wave per query ----------------
__global__ void aml_attn_k(const float* __restrict__ qkv, const int* __restrict__ offs,
                           float* __restrict__ o) {
    int t = blockIdx.x;
    int head = blockIdx.y;
    int start = offs[t], end = offs[t + 1];
    if (end <= start) return;
    int wave = threadIdx.x >> 6, lane = threadIdx.x & 63;
    int qoff = head * DHH;
    for (int qi = start + wave; qi < end; qi += 4) {
        float q = qkv[(size_t)qi * 768 + qoff + lane] * 0.125f;  // 1/sqrt(64)
        float m = -1e30f, s = 0.f, acc = 0.f;
        for (int j = start; j < end; ++j) {
            float p = q * qkv[(size_t)j * 768 + 256 + qoff + lane];
            #pragma unroll
            for (int off = 32; off; off >>= 1) p += __shfl_xor(p, off);
            float mn = fmaxf(m, p);
            float corr = __expf(m - mn);
            float pe = __expf(p - mn);
            s = s * corr + pe;
            acc = acc * corr + pe * qkv[(size_t)j * 768 + 512 + qoff + lane];
            m = mn;
        }
        o[(size_t)qi * DD + qoff + lane] = acc / s;
    }
}

// ---------------- residual + LayerNorm (in place on h) ----------------
__global__ void aml_ln_k(float* __restrict__ h, const float* __restrict__ r,
                         const float* __restrict__ g,
                         const float* __restrict__ b) {
    int i = blockIdx.x;
    int d = threadIdx.x;  // 256
    float v = h[(size_t)i * DD + d] + r[(size_t)i * DD + d];
    __shared__ float rs[256], rss[256];
    rs[d] = v; rss[d] = v * v;
    __syncthreads();
    for (int o = 128; o > 0; o >>= 1) {
        if (d < o) { rs[d] += rs[d + o]; rss[d] += rss[d + o]; }
        __syncthreads();
    }
    float mu = rs[0] / DD;
    float var = rss[0] / DD - mu * mu;
    float inv = rsqrtf(var + 1e-5f);
    h[(size_t)i * DD + d] = (v - mu) * inv * g[d] + b[d];
}

// ---------------- classifier ----------------
__global__ void aml_cls_k(const float* __restrict__ h, const float* __restrict__ w,
                          const float* __restrict__ b, float* __restrict__ out) {
    int idx = blockIdx.x * 256 + threadIdx.x;
    if (idx >= NN * 2) return;
    int i = idx >> 1, c = idx & 1;
    float acc = b[c];
    const float* wr = w + (size_t)c * DD;
    #pragma unroll 4
    for (int k = 0; k < DD; ++k) acc += h[(size_t)i * DD + k] * wr[k];
    out[idx] = acc;
}

extern "C" void kernel_launch(void* const* d_in, const int* in_sizes, int n_in,
                              void* d_out, int out_size, void* d_ws, size_t ws_size,
                              hipStream_t stream) {
    const float* x       = (const float*)d_in[0];
    const int*   ei      = (const int*)d_in[1];
    const int*   ts      = (const int*)d_in[2];
    const float* lin_l_w = (const float*)d_in[3];
    const float* lin_l_b = (const float*)d_in[4];
    const float* lin_r_w = (const float*)d_in[5];
    const float* bn_g    = (const float*)d_in[6];
    const float* bn_b    = (const float*)d_in[7];
    const float* inp_w   = (const float*)d_in[8];   // [2,768,256]
    const float* inp_b   = (const float*)d_in[9];   // [2,768]
    const float* out_w   = (const float*)d_in[10];  // [2,256,256]
    const float* out_b   = (const float*)d_in[11];
    const float* ff1_w   = (const float*)d_in[12];
    const float* ff1_b   = (const float*)d_in[13];
    const float* ff2_w   = (const float*)d_in[14];
    const float* ff2_b   = (const float*)d_in[15];
    const float* ln1_g   = (const float*)d_in[16];
    const float* ln1_b   = (const float*)d_in[17];
    const float* ln2_g   = (const float*)d_in[18];
    const float* ln2_b   = (const float*)d_in[19];
    const float* cls_w   = (const float*)d_in[20];
    const float* cls_b   = (const float*)d_in[21];

    float* ws    = (float*)d_ws;
    float* agg   = ws;                       // N*128
    float* cnt   = agg + (size_t)NN * DIN;   // N
    float* h     = cnt + NN;                 // N*256
    float* qkv   = h + (size_t)NN * DD;      // N*768
    float* t1    = qkv + (size_t)NN * 768;   // N*256
    float* t2    = t1 + (size_t)NN * DD;     // N*256
    float* stats = t2 + (size_t)NN * DD;     // 512
    int*   offs  = (int*)(stats + 512);      // 33

    // zero agg + cnt (adjacent)
    hipMemsetAsync(agg, 0, ((size_t)NN * DIN + NN) * sizeof(float), stream);

    aml_scatter_k<<<EE / 4, 256, 0, stream>>>(x, ei, agg, cnt);
    aml_sage_k<<<NN, 256, 0, stream>>>(x, agg, cnt, lin_l_w, lin_l_b, lin_r_w, h);
    aml_bn_stats_k<<<DD, 256, 0, stream>>>(h, stats);
    aml_bn_apply_k<<<(NN * DD) / 256, 256, 0, stream>>>(h, stats, bn_g, bn_b);
    aml_offsets_k<<<1, 64, 0, stream>>>(ts, offs);

    for (int l = 0; l < 2; ++l) {
        const float* wq = inp_w + (size_t)l * 768 * DD;
        const float* bq = inp_b + (size_t)l * 768;
        aml_lin_k<0><<<dim3(NN, 3), 256, 1024, stream>>>(h, wq, bq, qkv, DD, 768);
        aml_attn_k<<<dim3(TT, NH), 256, 0, stream>>>(qkv, offs, t1);
        aml_lin_k<0><<<dim3(NN, 1), 256, 1024, stream>>>(t1, out_w + (size_t)l * DD * DD,
                                                         out_b + (size_t)l * DD, t2, DD, DD);
        aml_ln_k<<<NN, 256, 0, stream>>>(h, t2, ln1_g + (size_t)l * DD, ln1_b + (size_t)l * DD);
        aml_lin_k<1><<<dim3(NN, 1), 256, 1024, stream>>>(h, ff1_w + (size_t)l * DD * DD,
                                                         ff1_b + (size_t)l * DD, t1, DD, DD);
        aml_lin_k<0><<<dim3(NN, 1), 256, 1024, stream>>>(t1, ff2_w + (size_t)l * DD * DD,
                                                         ff2_b + (size_t)l * DD, t2, DD, DD);
        aml_ln_k<<<NN, 256, 0, stream>>>(h, t2, ln2_g + (size_t)l * DD, ln2_b + (size_t)l * DD);
    }

    aml_cls_k<<<(NN * 2 + 255) / 256, 256, 0, stream>>>(h, cls_w, cls_b, (float*)d_out);
}

// Round 3
// 424.039 us; speedup vs baseline: 31.1628x; 31.1628x over previous
//
#include <hip/hip_runtime.h>

#define NN   6144
#define EE   98304
#define DIN  128
#define DD   256
#define TT   32
#define NH   4
#define DHH  64

typedef __attribute__((ext_vector_type(8))) short short8;
typedef __attribute__((ext_vector_type(4))) float f32x4;

__device__ __forceinline__ unsigned short f2bf(float f) {
    unsigned u = __float_as_uint(f);
    return (unsigned short)((u + 0x7fffu + ((u >> 16) & 1u)) >> 16);
}
__device__ __forceinline__ unsigned pk2(float a, float b) {
    return (unsigned)f2bf(a) | ((unsigned)f2bf(b) << 16);
}

// ---------------- scatter-mean aggregation ----------------
__global__ void aml_scatter_k(const float* __restrict__ x,
                              const int* __restrict__ ei,
                              float* __restrict__ agg, float* __restrict__ cnt) {
    int e = blockIdx.x * 4 + (threadIdx.x >> 6);
    int lane = threadIdx.x & 63;
    if (e >= EE) return;
    int src = ei[e];
    int dst = ei[EE + e];
    #pragma unroll
    for (int f = lane; f < DIN; f += 64) {
        atomicAdd(&agg[(size_t)dst * DIN + f], x[(size_t)src * DIN + f]);
    }
    if (lane == 0) atomicAdd(&cnt[dst], 1.0f);
}

// ---------------- build concat input [agg/cnt | x]  (f32) ----------------
__global__ void aml_ac_k(const float* __restrict__ x, const float* __restrict__ agg,
                         const float* __restrict__ cnt, float* __restrict__ ac) {
    int i = blockIdx.x;
    int d = threadIdx.x;  // 256
    float inv = 1.0f / fmaxf(cnt[i], 1.0f);
    float v = (d < DIN) ? agg[(size_t)i * DIN + d] * inv
                        : x[(size_t)i * DIN + (d - DIN)];
    ac[(size_t)i * DD + d] = v;
}

// ---------------- build concat weight [lin_l | lin_r] (f32) ----------------
__global__ void aml_wcat_k(const float* __restrict__ wl, const float* __restrict__ wr,
                           float* __restrict__ wcat) {
    int d = blockIdx.x;
    int k = threadIdx.x;  // 256
    wcat[(size_t)d * DD + k] = (k < DIN) ? wl[(size_t)d * DIN + k]
                                         : wr[(size_t)d * DIN + (k - DIN)];
}

// ---------------- MFMA GEMM: C[N x M] = A[N x 256] * W[M x 256]^T + bias ----------------
// 64x64 tile per 256-thread block; stages A and W f32->bf16 into XOR-swizzled LDS.
template <int RELU>
__global__ __launch_bounds__(256)
void aml_gemm_k(const float* __restrict__ A, const float* __restrict__ W,
                const float* __restrict__ bias, float* __restrict__ C, int M) {
    __shared__ __align__(16) unsigned char lds[65536];  // A: [0,32K) W: [32K,64K)
    const int t = threadIdx.x;
    const int brow = blockIdx.x * 64;
    const int bcol = blockIdx.y * 64;

    const float* srcA = A + (size_t)brow * 256;
    const float* srcW = W + (size_t)bcol * 256;
    #pragma unroll
    for (int p = 0; p < 8; ++p) {
        int c = t + p * 256;              // chunk 0..2047 (8 bf16 each)
        int row = c >> 5;
        int colb = (c & 31) * 16;         // byte col of chunk
        int dst = row * 512 + (colb ^ ((row & 7) << 4));
        const float* sA = srcA + row * 256 + (c & 31) * 8;
        const float* sW = srcW + row * 256 + (c & 31) * 8;
        float4 a0 = *(const float4*)sA;
        float4 a1 = *(const float4*)(sA + 4);
        uint4 pa = { pk2(a0.x, a0.y), pk2(a0.z, a0.w), pk2(a1.x, a1.y), pk2(a1.z, a1.w) };
        *(uint4*)(lds + dst) = pa;
        float4 w0 = *(const float4*)sW;
        float4 w1 = *(const float4*)(sW + 4);
        uint4 pw = { pk2(w0.x, w0.y), pk2(w0.z, w0.w), pk2(w1.x, w1.y), pk2(w1.z, w1.w) };
        *(uint4*)(lds + 32768 + dst) = pw;
    }
    __syncthreads();

    const int wave = t >> 6, lane = t & 63;
    const int lrow = lane & 15, lk = lane >> 4;  // lk 0..3
    const int arow = wave * 16 + lrow;
    f32x4 acc[4] = {};
    #pragma unroll
    for (int ks = 0; ks < 8; ++ks) {
        int kbyte = ks * 64 + lk * 16;
        short8 af = *(const short8*)(lds + arow * 512 + (kbyte ^ ((arow & 7) << 4)));
        #pragma unroll
        for (int ct = 0; ct < 4; ++ct) {
            int wrow = ct * 16 + lrow;
            short8 bf = *(const short8*)(lds + 32768 + wrow * 512 + (kbyte ^ ((wrow & 7) << 4)));
            acc[ct] = __builtin_amdgcn_mfma_f32_16x16x32_bf16(af, bf, acc[ct], 0, 0, 0);
        }
    }

    #pragma unroll
    for (int ct = 0; ct < 4; ++ct) {
        int col = bcol + ct * 16 + lrow;
        float bv = bias[col];
        #pragma unroll
        for (int r = 0; r < 4; ++r) {
            int grow = brow + wave * 16 + lk * 4 + r;
            float v = acc[ct][r] + bv;
            if (RELU) v = fmaxf(v, 0.0f);
            C[(size_t)grow * M + col] = v;
        }
    }
}

// ---------------- BatchNorm column stats ----------------
__global__ void aml_bn_stats_k(const float* __restrict__ h, float* __restrict__ stats) {
    int d = blockIdx.x;
    int t = threadIdx.x;
    float s = 0.f, ss = 0.f;
    for (int i = t; i < NN; i += 256) {
        float v = h[(size_t)i * DD + d];
        s += v; ss += v * v;
    }
    __shared__ float rs[256], rss[256];
    rs[t] = s; rss[t] = ss;
    __syncthreads();
    for (int o = 128; o > 0; o >>= 1) {
        if (t < o) { rs[t] += rs[t + o]; rss[t] += rss[t + o]; }
        __syncthreads();
    }
    if (t == 0) {
        float mu = rs[0] / NN;
        float var = rss[0] / NN - mu * mu;
        stats[d] = mu;
        stats[DD + d] = rsqrtf(var + 1e-5f);
    }
}

__global__ void aml_bn_apply_k(float* __restrict__ h, const float* __restrict__ stats,
                               const float* __restrict__ g, const float* __restrict__ b) {
    int idx = blockIdx.x * 256 + threadIdx.x;
    if (idx >= NN * DD) return;
    int d = idx & (DD - 1);
    float v = (h[idx] - stats[d]) * stats[DD + d] * g[d] + b[d];
    h[idx] = fmaxf(v, 0.0f);
}

// ---------------- timestep segment offsets ----------------
__global__ void aml_offsets_k(const int* __restrict__ ts, int* __restrict__ offs) {
    int t = threadIdx.x;
    if (t > TT) return;
    int lo = 0, hi = NN;
    while (lo < hi) {
        int mid = (lo + hi) >> 1;
        if (ts[mid] < t) lo = mid + 1; else hi = mid;
    }
    offs[t] = lo;
}

// ---------------- block-diagonal attention v2 ----------------
// grid (TT, NH, 8); per WG: stage 64-key tiles (K^T pad65, V pad68), lanes=keys
// for scores, lanes=d for PV; online softmax state in unrolled register slots.
#define QSLOTS 12
__global__ __launch_bounds__(256)
void aml_attn_k(const float* __restrict__ qkv, const int* __restrict__ offs,
                float* __restrict__ o) {
    int tb = blockIdx.x, head = blockIdx.y, z = blockIdx.z;
    int start = offs[tb], end = offs[tb + 1];
    int S = end - start;
    if (S <= 0) return;
    int t = threadIdx.x;
    int wave = t >> 6, lane = t & 63;
    int qoff = head * DHH;

    __shared__ float KT[64][65];   // [d][j]
    __shared__ float Vs[64][68];   // [j][d]
    __shared__ float qly[4][64];
    __shared__ float ply[4][64];

    float qreg[QSLOTS], mreg[QSLOTS], sreg[QSLOTS], areg[QSLOTS];
    #pragma unroll
    for (int s = 0; s < QSLOTS; ++s) {
        int qi = start + z * 4 + wave + 32 * s;
        qreg[s] = (qi < end) ? qkv[(size_t)qi * 768 + qoff + lane] * 0.125f : 0.f;
        mreg[s] = -1e30f; sreg[s] = 0.f; areg[s] = 0.f;
    }

    int ntile = (S + 63) >> 6;
    for (int tile = 0; tile < ntile; ++tile) {
        int jcnt = S - tile * 64; if (jcnt > 64) jcnt = 64;
        // stage tile: thread -> key j = t>>2, d-range (t&3)*16..+15
        {
            int j = t >> 2, d0 = (t & 3) * 16;
            if (j < jcnt) {
                const float* kp = qkv + (size_t)(start + tile * 64 + j) * 768 + 256 + qoff + d0;
                const float* vp = kp + 256;
                #pragma unroll
                for (int q4 = 0; q4 < 4; ++q4) {
                    float4 kv = *(const float4*)(kp + q4 * 4);
                    KT[d0 + q4 * 4 + 0][j] = kv.x;
                    KT[d0 + q4 * 4 + 1][j] = kv.y;
                    KT[d0 + q4 * 4 + 2][j] = kv.z;
                    KT[d0 + q4 * 4 + 3][j] = kv.w;
                    *(float4*)(&Vs[j][d0 + q4 * 4]) = *(const float4*)(vp + q4 * 4);
                }
            }
        }
        __syncthreads();

        #pragma unroll
        for (int s = 0; s < QSLOTS; ++s) {
            int qi = start + z * 4 + wave + 32 * s;
            if (qi < end) {
                qly[wave][lane] = qreg[s];
                // scores: lane = key j
                float sc = 0.f;
                #pragma unroll 8
                for (int d = 0; d < 64; ++d) sc += qly[wave][d] * KT[d][lane];
                sc = (lane < jcnt) ? sc : -1e30f;
                // reduce max
                float pm = sc;
                #pragma unroll
                for (int off = 32; off; off >>= 1) pm = fmaxf(pm, __shfl_xor(pm, off));
                float mn = fmaxf(mreg[s], pm);
                float corr = __expf(mreg[s] - mn);
                float p = (lane < jcnt) ? __expf(sc - mn) : 0.f;
                float ps = p;
                #pragma unroll
                for (int off = 32; off; off >>= 1) ps += __shfl_xor(ps, off);
                ply[wave][lane] = p;
                sreg[s] = sreg[s] * corr + ps;
                mreg[s] = mn;
                // PV: lane = d
                float a = areg[s] * corr;
                for (int j = 0; j < jcnt; ++j) a += ply[wave][j] * Vs[j][lane];
                areg[s] = a;
            }
        }
        __syncthreads();
    }

    #pragma unroll
    for (int s = 0; s < QSLOTS; ++s) {
        int qi = start + z * 4 + wave + 32 * s;
        if (qi < end) o[(size_t)qi * DD + qoff + lane] = areg[s] / sreg[s];
    }
}

// ---------------- residual + LayerNorm (in place on h) ----------------
__global__ void aml_ln_k(float* __restrict__ h, const float* __restrict__ r,
                         const float* __restrict__ g, const float* __restrict__ b) {
    int i = blockIdx.x;
    int d = threadIdx.x;
    float v = h[(size_t)i * DD + d] + r[(size_t)i * DD + d];
    __shared__ float rs[256], rss[256];
    rs[d] = v; rss[d] = v * v;
    __syncthreads();
    for (int o = 128; o > 0; o >>= 1) {
        if (d < o) { rs[d] += rs[d + o]; rss[d] += rss[d + o]; }
        __syncthreads();
    }
    float mu = rs[0] / DD;
    float var = rss[0] / DD - mu * mu;
    float inv = rsqrtf(var + 1e-5f);
    h[(size_t)i * DD + d] = (v - mu) * inv * g[d] + b[d];
}

// ---------------- classifier ----------------
__global__ void aml_cls_k(const float* __restrict__ h, const float* __restrict__ w,
                          const float* __restrict__ b, float* __restrict__ out) {
    int idx = blockIdx.x * 256 + threadIdx.x;
    if (idx >= NN * 2) return;
    int i = idx >> 1, c = idx & 1;
    float acc = b[c];
    const float* wr = w + (size_t)c * DD;
    #pragma unroll 4
    for (int k = 0; k < DD; ++k) acc += h[(size_t)i * DD + k] * wr[k];
    out[idx] = acc;
}

extern "C" void kernel_launch(void* const* d_in, const int* in_sizes, int n_in,
                              void* d_out, int out_size, void* d_ws, size_t ws_size,
                              hipStream_t stream) {
    const float* x       = (const float*)d_in[0];
    const int*   ei      = (const int*)d_in[1];
    const int*   ts      = (const int*)d_in[2];
    const float* lin_l_w = (const float*)d_in[3];
    const float* lin_l_b = (const float*)d_in[4];
    const float* lin_r_w = (const float*)d_in[5];
    const float* bn_g    = (const float*)d_in[6];
    const float* bn_b    = (const float*)d_in[7];
    const float* inp_w   = (const float*)d_in[8];
    const float* inp_b   = (const float*)d_in[9];
    const float* out_w   = (const float*)d_in[10];
    const float* out_b   = (const float*)d_in[11];
    const float* ff1_w   = (const float*)d_in[12];
    const float* ff1_b   = (const float*)d_in[13];
    const float* ff2_w   = (const float*)d_in[14];
    const float* ff2_b   = (const float*)d_in[15];
    const float* ln1_g   = (const float*)d_in[16];
    const float* ln1_b   = (const float*)d_in[17];
    const float* ln2_g   = (const float*)d_in[18];
    const float* ln2_b   = (const float*)d_in[19];
    const float* cls_w   = (const float*)d_in[20];
    const float* cls_b   = (const float*)d_in[21];

    float* ws    = (float*)d_ws;
    float* agg   = ws;                       // N*128
    float* cnt   = agg + (size_t)NN * DIN;   // N
    float* h     = cnt + NN;                 // N*256
    float* qkv   = h + (size_t)NN * DD;      // N*768
    float* t1    = qkv + (size_t)NN * 768;   // N*256
    float* t2    = t1 + (size_t)NN * DD;     // N*256
    float* stats = t2 + (size_t)NN * DD;     // 512
    int*   offs  = (int*)(stats + 512);      // 33
    float* ac    = qkv;                      // alias: concat input  [N*256]
    float* wcat  = t1;                       // alias: concat weight [256*256]

    hipMemsetAsync(agg, 0, ((size_t)NN * DIN + NN) * sizeof(float), stream);

    aml_scatter_k<<<EE / 4, 256, 0, stream>>>(x, ei, agg, cnt);
    aml_ac_k<<<NN, 256, 0, stream>>>(x, agg, cnt, ac);
    aml_wcat_k<<<DD, 256, 0, stream>>>(lin_l_w, lin_r_w, wcat);
    aml_offsets_k<<<1, 64, 0, stream>>>(ts, offs);
    aml_gemm_k<0><<<dim3(NN / 64, 4), 256, 0, stream>>>(ac, wcat, lin_l_b, h, DD);
    aml_bn_stats_k<<<DD, 256, 0, stream>>>(h, stats);
    aml_bn_apply_k<<<(NN * DD) / 256, 256, 0, stream>>>(h, stats, bn_g, bn_b);

    for (int l = 0; l < 2; ++l) {
        aml_gemm_k<0><<<dim3(NN / 64, 12), 256, 0, stream>>>(h, inp_w + (size_t)l * 768 * DD,
                                                             inp_b + (size_t)l * 768, qkv, 768);
        aml_attn_k<<<dim3(TT, NH, 8), 256, 0, stream>>>(qkv, offs, t1);
        aml_gemm_k<0><<<dim3(NN / 64, 4), 256, 0, stream>>>(t1, out_w + (size_t)l * DD * DD,
                                                            out_b + (size_t)l * DD, t2, DD);
        aml_ln_k<<<NN, 256, 0, stream>>>(h, t2, ln1_g + (size_t)l * DD, ln1_b + (size_t)l * DD);
        aml_gemm_k<1><<<dim3(NN / 64, 4), 256, 0, stream>>>(h, ff1_w + (size_t)l * DD * DD,
                                                            ff1_b + (size_t)l * DD, t1, DD);
        aml_gemm_k<0><<<dim3(NN / 64, 4), 256, 0, stream>>>(t1, ff2_w + (size_t)l * DD * DD,
                                                            ff2_b + (size_t)l * DD, t2, DD);
        aml_ln_k<<<NN, 256, 0, stream>>>(h, t2, ln2_g + (size_t)l * DD, ln2_b + (size_t)l * DD);
    }

    aml_cls_k<<<(NN * 2 + 255) / 256, 256, 0, stream>>>(h, cls_w, cls_b, (float*)d_out);
}

// Round 4
// 201.220 us; speedup vs baseline: 65.6705x; 2.1073x over previous
//
#include <hip/hip_runtime.h>

#define NN   6144
#define EE   98304
#define DIN  128
#define DD   256
#define TT   32
#define NH   4
#define ATTN_Z 6

typedef __attribute__((ext_vector_type(8))) short short8;
typedef __attribute__((ext_vector_type(4))) float f32x4;

__device__ __forceinline__ unsigned short f2bf(float f) {
    unsigned u = __float_as_uint(f);
    return (unsigned short)((u + 0x7fffu + ((u >> 16) & 1u)) >> 16);
}
__device__ __forceinline__ unsigned pk2(float a, float b) {
    return (unsigned)f2bf(a) | ((unsigned)f2bf(b) << 16);
}
__device__ __forceinline__ short8 pack8(float4 a, float4 b, float s) {
    union { unsigned u[4]; short8 v; } r;
    r.u[0] = pk2(a.x * s, a.y * s);
    r.u[1] = pk2(a.z * s, a.w * s);
    r.u[2] = pk2(b.x * s, b.y * s);
    r.u[3] = pk2(b.z * s, b.w * s);
    return r.v;
}

// ---------------- scatter-mean aggregation ----------------
__global__ void aml_scatter_k(const float* __restrict__ x,
                              const int* __restrict__ ei,
                              float* __restrict__ agg, float* __restrict__ cnt) {
    int e = blockIdx.x * 4 + (threadIdx.x >> 6);
    int lane = threadIdx.x & 63;
    if (e >= EE) return;
    int src = ei[e];
    int dst = ei[EE + e];
    #pragma unroll
    for (int f = lane; f < DIN; f += 64) {
        atomicAdd(&agg[(size_t)dst * DIN + f], x[(size_t)src * DIN + f]);
    }
    if (lane == 0) atomicAdd(&cnt[dst], 1.0f);
}

// ---------------- build concat input [agg/cnt | x] ----------------
__global__ void aml_ac_k(const float* __restrict__ x, const float* __restrict__ agg,
                         const float* __restrict__ cnt, float* __restrict__ ac) {
    int i = blockIdx.x;
    int d = threadIdx.x;
    float inv = 1.0f / fmaxf(cnt[i], 1.0f);
    float v = (d < DIN) ? agg[(size_t)i * DIN + d] * inv
                        : x[(size_t)i * DIN + (d - DIN)];
    ac[(size_t)i * DD + d] = v;
}

// ---------------- build concat weight [lin_l | lin_r] ----------------
__global__ void aml_wcat_k(const float* __restrict__ wl, const float* __restrict__ wr,
                           float* __restrict__ wcat) {
    int d = blockIdx.x;
    int k = threadIdx.x;
    wcat[(size_t)d * DD + k] = (k < DIN) ? wl[(size_t)d * DIN + k]
                                         : wr[(size_t)d * DIN + (k - DIN)];
}

// ---------------- MFMA GEMM: C[N x M] = A[N x 256] * W[M x 256]^T + bias ----------------
template <int RELU>
__global__ __launch_bounds__(256)
void aml_gemm_k(const float* __restrict__ A, const float* __restrict__ W,
                const float* __restrict__ bias, float* __restrict__ C, int M) {
    __shared__ __align__(16) unsigned char lds[65536];
    const int t = threadIdx.x;
    const int brow = blockIdx.x * 64;
    const int bcol = blockIdx.y * 64;

    const float* srcA = A + (size_t)brow * 256;
    const float* srcW = W + (size_t)bcol * 256;
    #pragma unroll
    for (int p = 0; p < 8; ++p) {
        int c = t + p * 256;
        int row = c >> 5;
        int colb = (c & 31) * 16;
        int dst = row * 512 + (colb ^ ((row & 7) << 4));
        const float* sA = srcA + row * 256 + (c & 31) * 8;
        const float* sW = srcW + row * 256 + (c & 31) * 8;
        float4 a0 = *(const float4*)sA;
        float4 a1 = *(const float4*)(sA + 4);
        uint4 pa = { pk2(a0.x, a0.y), pk2(a0.z, a0.w), pk2(a1.x, a1.y), pk2(a1.z, a1.w) };
        *(uint4*)(lds + dst) = pa;
        float4 w0 = *(const float4*)sW;
        float4 w1 = *(const float4*)(sW + 4);
        uint4 pw = { pk2(w0.x, w0.y), pk2(w0.z, w0.w), pk2(w1.x, w1.y), pk2(w1.z, w1.w) };
        *(uint4*)(lds + 32768 + dst) = pw;
    }
    __syncthreads();

    const int wave = t >> 6, lane = t & 63;
    const int lrow = lane & 15, lk = lane >> 4;
    const int arow = wave * 16 + lrow;
    f32x4 acc[4] = {};
    #pragma unroll
    for (int ks = 0; ks < 8; ++ks) {
        int kbyte = ks * 64 + lk * 16;
        short8 af = *(const short8*)(lds + arow * 512 + (kbyte ^ ((arow & 7) << 4)));
        #pragma unroll
        for (int ct = 0; ct < 4; ++ct) {
            int wrow = ct * 16 + lrow;
            short8 bf = *(const short8*)(lds + 32768 + wrow * 512 + (kbyte ^ ((wrow & 7) << 4)));
            acc[ct] = __builtin_amdgcn_mfma_f32_16x16x32_bf16(af, bf, acc[ct], 0, 0, 0);
        }
    }

    #pragma unroll
    for (int ct = 0; ct < 4; ++ct) {
        int col = bcol + ct * 16 + lrow;
        float bv = bias[col];
        #pragma unroll
        for (int r = 0; r < 4; ++r) {
            int grow = brow + wave * 16 + lk * 4 + r;
            float v = acc[ct][r] + bv;
            if (RELU) v = fmaxf(v, 0.0f);
            C[(size_t)grow * M + col] = v;
        }
    }
}

// ---------------- BatchNorm stats: coalesced rows, atomic partials ----------------
__global__ void aml_bn_stats_k(const float* __restrict__ h, float* __restrict__ stats) {
    int d = threadIdx.x;
    int r0 = blockIdx.x * 96;
    float s = 0.f, ss = 0.f;
    for (int i = 0; i < 96; ++i) {
        float v = h[(size_t)(r0 + i) * DD + d];
        s += v; ss += v * v;
    }
    atomicAdd(&stats[d], s);
    atomicAdd(&stats[DD + d], ss);
}

__global__ void aml_bn_apply_k(float* __restrict__ h, const float* __restrict__ stats,
                               const float* __restrict__ g, const float* __restrict__ b) {
    int idx = blockIdx.x * 256 + threadIdx.x;
    int d = idx & (DD - 1);
    float mu = stats[d] * (1.0f / NN);
    float var = stats[DD + d] * (1.0f / NN) - mu * mu;
    float v = (h[idx] - mu) * rsqrtf(var + 1e-5f) * g[d] + b[d];
    h[idx] = fmaxf(v, 0.0f);
}

// ---------------- timestep segment offsets ----------------
__global__ void aml_offsets_k(const int* __restrict__ ts, int* __restrict__ offs) {
    int t = threadIdx.x;
    if (t > TT) return;
    int lo = 0, hi = NN;
    while (lo < hi) {
        int mid = (lo + hi) >> 1;
        if (ts[mid] < t) lo = mid + 1; else hi = mid;
    }
    offs[t] = lo;
}

// ---------------- MFMA flash attention over block-diagonal segments ----------------
// grid (TT, NH, ATTN_Z); WG = 4 waves, each wave owns 16 q-rows.
// S^T = mfma(K, Q) so softmax per q is a 16-lane-group reduce; P relayout via
// wave-private swizzled LDS; PV = mfma(Vt, P) accumulates O^T.
__global__ __launch_bounds__(256)
void aml_attn_k(const float* __restrict__ qkv, const int* __restrict__ offs,
                float* __restrict__ o) {
    int tb = blockIdx.x, head = blockIdx.y, z = blockIdx.z;
    int start = offs[tb], end = offs[tb + 1];
    int S = end - start;
    if (S <= z * 64) return;
    int t = threadIdx.x, wave = t >> 6, lane = t & 63;
    int lq = lane & 15, lk = lane >> 4;
    int qoff = head * 64;

    __shared__ __align__(16) unsigned char Kl[8192];     // [64k][64d] bf16, swizzled
    __shared__ __align__(16) unsigned char Vt[8192];     // [64d][64k] bf16, swizzled
    __shared__ __align__(16) unsigned char Pl[4][2048];  // per-wave [16q][64k] bf16, swizzled
    __shared__ float Ol[4][16][65];                      // per-wave O scratch f32, padded

    // Q fragments in registers (scaled by 1/sqrt(64))
    int qi = start + z * 64 + wave * 16 + lq;
    int qic = min(qi, end - 1);
    const float* qp = qkv + (size_t)qic * 768 + qoff + lk * 8;
    short8 qf[2];
    #pragma unroll
    for (int ks = 0; ks < 2; ++ks) {
        float4 a = *(const float4*)(qp + ks * 32);
        float4 b = *(const float4*)(qp + ks * 32 + 4);
        qf[ks] = pack8(a, b, 0.125f);
    }

    float m = -1e30f, l = 0.f;
    f32x4 acc[4] = {};

    int ntile = (S + 63) >> 6;
    for (int tile = 0; tile < ntile; ++tile) {
        int jcnt = S - tile * 64; if (jcnt > 64) jcnt = 64;
        // ---- stage K (row-major swz) and V (transposed swz), zero-fill tail ----
        {
            int j = t >> 2, d0 = (t & 3) * 16;
            unsigned char* krow = Kl + j * 128;
            if (j < jcnt) {
                const float* kp = qkv + (size_t)(start + tile * 64 + j) * 768 + 256 + qoff + d0;
                float4 k0 = *(const float4*)kp, k1 = *(const float4*)(kp + 4);
                float4 k2 = *(const float4*)(kp + 8), k3 = *(const float4*)(kp + 12);
                uint4 pc0 = { pk2(k0.x, k0.y), pk2(k0.z, k0.w), pk2(k1.x, k1.y), pk2(k1.z, k1.w) };
                uint4 pc1 = { pk2(k2.x, k2.y), pk2(k2.z, k2.w), pk2(k3.x, k3.y), pk2(k3.z, k3.w) };
                *(uint4*)(krow + ((d0 * 2) ^ ((j & 7) << 4))) = pc0;
                *(uint4*)(krow + ((d0 * 2 + 16) ^ ((j & 7) << 4))) = pc1;
                const float* vp = kp + 256;
                float4 v0 = *(const float4*)vp, v1 = *(const float4*)(vp + 4);
                float4 v2 = *(const float4*)(vp + 8), v3 = *(const float4*)(vp + 12);
                float vv[16] = { v0.x, v0.y, v0.z, v0.w, v1.x, v1.y, v1.z, v1.w,
                                 v2.x, v2.y, v2.z, v2.w, v3.x, v3.y, v3.z, v3.w };
                #pragma unroll
                for (int i = 0; i < 16; ++i) {
                    int d = d0 + i;
                    *(unsigned short*)(Vt + d * 128 + ((j * 2) ^ ((d & 7) << 4))) = f2bf(vv[i]);
                }
            } else {
                uint4 zz = { 0, 0, 0, 0 };
                *(uint4*)(krow + ((d0 * 2) ^ ((j & 7) << 4))) = zz;
                *(uint4*)(krow + ((d0 * 2 + 16) ^ ((j & 7) << 4))) = zz;
                #pragma unroll
                for (int i = 0; i < 16; ++i) {
                    int d = d0 + i;
                    *(unsigned short*)(Vt + d * 128 + ((j * 2) ^ ((d & 7) << 4))) = 0;
                }
            }
        }
        __syncthreads();

        // ---- S^T = K · Q^T : 4 kt tiles ----
        f32x4 sv[4];
        #pragma unroll
        for (int kt = 0; kt < 4; ++kt) {
            int kr = kt * 16 + lq;
            f32x4 s = {};
            #pragma unroll
            for (int ks = 0; ks < 2; ++ks) {
                short8 kf = *(const short8*)(Kl + kr * 128 + ((ks * 64 + lk * 16) ^ ((kr & 7) << 4)));
                s = __builtin_amdgcn_mfma_f32_16x16x32_bf16(kf, qf[ks], s, 0, 0, 0);
            }
            sv[kt] = s;
        }
        // ---- mask + online softmax (per q = lane&15 column) ----
        float pm = -1e30f;
        #pragma unroll
        for (int kt = 0; kt < 4; ++kt) {
            #pragma unroll
            for (int r = 0; r < 4; ++r) {
                int kk = tile * 64 + kt * 16 + lk * 4 + r;
                float s = (kk < S) ? sv[kt][r] : -1e30f;
                sv[kt][r] = s;
                pm = fmaxf(pm, s);
            }
        }
        pm = fmaxf(pm, __shfl_xor(pm, 16));
        pm = fmaxf(pm, __shfl_xor(pm, 32));
        float mn = fmaxf(m, pm);
        float corr = __expf(m - mn);
        m = mn;
        float ps = 0.f;
        #pragma unroll
        for (int kt = 0; kt < 4; ++kt) {
            #pragma unroll
            for (int r = 0; r < 4; ++r) {
                float p = __expf(sv[kt][r] - mn);
                sv[kt][r] = p;
                ps += p;
            }
            uint2 w = { pk2(sv[kt][0], sv[kt][1]), pk2(sv[kt][2], sv[kt][3]) };
            *(uint2*)(Pl[wave] + lq * 128 + ((kt * 32 + lk * 8) ^ ((lq & 7) << 4))) = w;
        }
        ps += __shfl_xor(ps, 16);
        ps += __shfl_xor(ps, 32);
        l = l * corr + ps;
        #pragma unroll
        for (int dt = 0; dt < 4; ++dt) {
            #pragma unroll
            for (int r = 0; r < 4; ++r) acc[dt][r] *= corr;
        }
        // ---- O^T += Vt · P ----
        #pragma unroll
        for (int ks = 0; ks < 2; ++ks) {
            short8 pf = *(const short8*)(Pl[wave] + lq * 128 + ((ks * 64 + lk * 16) ^ ((lq & 7) << 4)));
            #pragma unroll
            for (int dt = 0; dt < 4; ++dt) {
                int dr = dt * 16 + lq;
                short8 vf = *(const short8*)(Vt + dr * 128 + ((ks * 64 + lk * 16) ^ ((dr & 7) << 4)));
                acc[dt] = __builtin_amdgcn_mfma_f32_16x16x32_bf16(vf, pf, acc[dt], 0, 0, 0);
            }
        }
        __syncthreads();
    }

    // ---- transpose O through LDS, coalesced store ----
    float linv = 1.0f / l;
    #pragma unroll
    for (int dt = 0; dt < 4; ++dt) {
        #pragma unroll
        for (int r = 0; r < 4; ++r)
            Ol[wave][lq][dt * 16 + lk * 4 + r] = acc[dt][r] * linv;
    }
    int q2 = lane >> 2, c2 = lane & 3;
    int qg = start + z * 64 + wave * 16 + q2;
    if (qg < end) {
        float* op = o + (size_t)qg * DD + qoff + c2 * 16;
        const float* sp = &Ol[wave][q2][c2 * 16];
        #pragma unroll
        for (int i = 0; i < 4; ++i) ((float4*)op)[i] = *(const float4*)(sp + i * 4);
    }
}

// ---------------- residual + LayerNorm: wave per row ----------------
__global__ void aml_ln_k(float* __restrict__ h, const float* __restrict__ r,
                         const float* __restrict__ g, const float* __restrict__ b) {
    int row = blockIdx.x * 4 + (threadIdx.x >> 6);
    int lane = threadIdx.x & 63;
    float* hp = h + (size_t)row * DD + lane * 4;
    float4 v = *(const float4*)hp;
    float4 rv = *(const float4*)(r + (size_t)row * DD + lane * 4);
    v.x += rv.x; v.y += rv.y; v.z += rv.z; v.w += rv.w;
    float s = v.x + v.y + v.z + v.w;
    float ss = v.x * v.x + v.y * v.y + v.z * v.z + v.w * v.w;
    #pragma unroll
    for (int off = 32; off; off >>= 1) {
        s += __shfl_xor(s, off);
        ss += __shfl_xor(ss, off);
    }
    float mu = s * (1.0f / DD);
    float var = ss * (1.0f / DD) - mu * mu;
    float inv = rsqrtf(var + 1e-5f);
    float4 gv = *(const float4*)(g + lane * 4);
    float4 bv = *(const float4*)(b + lane * 4);
    v.x = (v.x - mu) * inv * gv.x + bv.x;
    v.y = (v.y - mu) * inv * gv.y + bv.y;
    v.z = (v.z - mu) * inv * gv.z + bv.z;
    v.w = (v.w - mu) * inv * gv.w + bv.w;
    *(float4*)hp = v;
}

// ---------------- classifier: wave per row ----------------
__global__ void aml_cls_k(const float* __restrict__ h, const float* __restrict__ w,
                          const float* __restrict__ b, float* __restrict__ out) {
    int row = blockIdx.x * 4 + (threadIdx.x >> 6);
    int lane = threadIdx.x & 63;
    float4 v = *(const float4*)(h + (size_t)row * DD + lane * 4);
    float4 w0 = *(const float4*)(w + lane * 4);
    float4 w1 = *(const float4*)(w + DD + lane * 4);
    float a0 = v.x * w0.x + v.y * w0.y + v.z * w0.z + v.w * w0.w;
    float a1 = v.x * w1.x + v.y * w1.y + v.z * w1.z + v.w * w1.w;
    #pragma unroll
    for (int off = 32; off; off >>= 1) {
        a0 += __shfl_xor(a0, off);
        a1 += __shfl_xor(a1, off);
    }
    if (lane == 0) {
        out[row * 2]     = a0 + b[0];
        out[row * 2 + 1] = a1 + b[1];
    }
}

extern "C" void kernel_launch(void* const* d_in, const int* in_sizes, int n_in,
                              void* d_out, int out_size, void* d_ws, size_t ws_size,
                              hipStream_t stream) {
    const float* x       = (const float*)d_in[0];
    const int*   ei      = (const int*)d_in[1];
    const int*   ts      = (const int*)d_in[2];
    const float* lin_l_w = (const float*)d_in[3];
    const float* lin_l_b = (const float*)d_in[4];
    const float* lin_r_w = (const float*)d_in[5];
    const float* bn_g    = (const float*)d_in[6];
    const float* bn_b    = (const float*)d_in[7];
    const float* inp_w   = (const float*)d_in[8];
    const float* inp_b   = (const float*)d_in[9];
    const float* out_w   = (const float*)d_in[10];
    const float* out_b   = (const float*)d_in[11];
    const float* ff1_w   = (const float*)d_in[12];
    const float* ff1_b   = (const float*)d_in[13];
    const float* ff2_w   = (const float*)d_in[14];
    const float* ff2_b   = (const float*)d_in[15];
    const float* ln1_g   = (const float*)d_in[16];
    const float* ln1_b   = (const float*)d_in[17];
    const float* ln2_g   = (const float*)d_in[18];
    const float* ln2_b   = (const float*)d_in[19];
    const float* cls_w   = (const float*)d_in[20];
    const float* cls_b   = (const float*)d_in[21];

    float* ws    = (float*)d_ws;
    float* agg   = ws;                         // N*128
    float* cnt   = agg + (size_t)NN * DIN;     // N
    float* stats = cnt + NN;                   // 512
    int*   offs  = (int*)(stats + 512);        // 64
    float* h     = stats + 512 + 64;           // N*256
    float* qkv   = h + (size_t)NN * DD;        // N*768
    float* t1    = qkv + (size_t)NN * 768;     // N*256
    float* t2    = t1 + (size_t)NN * DD;       // N*256
    float* ac    = qkv;                        // alias
    float* wcat  = t1;                         // alias

    // zero agg + cnt + stats in one shot (adjacent)
    hipMemsetAsync(agg, 0, ((size_t)NN * DIN + NN + 512) * sizeof(float), stream);

    aml_scatter_k<<<EE / 4, 256, 0, stream>>>(x, ei, agg, cnt);
    aml_ac_k<<<NN, 256, 0, stream>>>(x, agg, cnt, ac);
    aml_wcat_k<<<DD, 256, 0, stream>>>(lin_l_w, lin_r_w, wcat);
    aml_offsets_k<<<1, 64, 0, stream>>>(ts, offs);
    aml_gemm_k<0><<<dim3(NN / 64, 4), 256, 0, stream>>>(ac, wcat, lin_l_b, h, DD);
    aml_bn_stats_k<<<64, 256, 0, stream>>>(h, stats);
    aml_bn_apply_k<<<(NN * DD) / 256, 256, 0, stream>>>(h, stats, bn_g, bn_b);

    for (int l = 0; l < 2; ++l) {
        aml_gemm_k<0><<<dim3(NN / 64, 12), 256, 0, stream>>>(h, inp_w + (size_t)l * 768 * DD,
                                                             inp_b + (size_t)l * 768, qkv, 768);
        aml_attn_k<<<dim3(TT, NH, ATTN_Z), 256, 0, stream>>>(qkv, offs, t1);
        aml_gemm_k<0><<<dim3(NN / 64, 4), 256, 0, stream>>>(t1, out_w + (size_t)l * DD * DD,
                                                            out_b + (size_t)l * DD, t2, DD);
        aml_ln_k<<<NN / 4, 256, 0, stream>>>(h, t2, ln1_g + (size_t)l * DD, ln1_b + (size_t)l * DD);
        aml_gemm_k<1><<<dim3(NN / 64, 4), 256, 0, stream>>>(h, ff1_w + (size_t)l * DD * DD,
                                                            ff1_b + (size_t)l * DD, t1, DD);
        aml_gemm_k<0><<<dim3(NN / 64, 4), 256, 0, stream>>>(t1, ff2_w + (size_t)l * DD * DD,
                                                            ff2_b + (size_t)l * DD, t2, DD);
        aml_ln_k<<<NN / 4, 256, 0, stream>>>(h, t2, ln2_g + (size_t)l * DD, ln2_b + (size_t)l * DD);
    }

    aml_cls_k<<<NN / 4, 256, 0, stream>>>(h, cls_w, cls_b, (float*)d_out);
}

// Round 5
// 183.540 us; speedup vs baseline: 71.9964x; 1.0963x over previous
//
#include <hip/hip_runtime.h>

#define NN   6144
#define EE   98304
#define DIN  128
#define DD   256
#define TT   32
#define NH   4
#define ATTN_Z 6

typedef __attribute__((ext_vector_type(8))) short short8;
typedef __attribute__((ext_vector_type(4))) float f32x4;

__device__ __forceinline__ unsigned short f2bf(float f) {
    unsigned u = __float_as_uint(f);
    return (unsigned short)((u + 0x7fffu + ((u >> 16) & 1u)) >> 16);
}
__device__ __forceinline__ unsigned pk2(float a, float b) {
    return (unsigned)f2bf(a) | ((unsigned)f2bf(b) << 16);
}
__device__ __forceinline__ short8 pack8(float4 a, float4 b, float s) {
    union { unsigned u[4]; short8 v; } r;
    r.u[0] = pk2(a.x * s, a.y * s);
    r.u[1] = pk2(a.z * s, a.w * s);
    r.u[2] = pk2(b.x * s, b.y * s);
    r.u[3] = pk2(b.z * s, b.w * s);
    return r.v;
}

// ---------------- CSR build: histogram ----------------
__global__ void aml_hist_k(const int* __restrict__ ei, int* __restrict__ deg) {
    int e = blockIdx.x * 256 + threadIdx.x;
    if (e < EE) atomicAdd(&deg[ei[EE + e]], 1);
}

// ---------------- CSR build: exclusive scan (one block, 256 x 24) ----------------
__global__ void aml_scan_k(const int* __restrict__ deg, int* __restrict__ rowptr,
                           int* __restrict__ cursor) {
    int t = threadIdx.x;
    int base = t * 24;
    int loc[24];
    int s = 0;
    #pragma unroll
    for (int j = 0; j < 24; ++j) { loc[j] = s; s += deg[base + j]; }
    __shared__ int part[256];
    part[t] = s;
    __syncthreads();
    // Hillis-Steele inclusive scan
    for (int o = 1; o < 256; o <<= 1) {
        int v = (t >= o) ? part[t - o] : 0;
        __syncthreads();
        part[t] += v;
        __syncthreads();
    }
    int off = (t > 0) ? part[t - 1] : 0;
    #pragma unroll
    for (int j = 0; j < 24; ++j) {
        rowptr[base + j] = off + loc[j];
        cursor[base + j] = off + loc[j];
    }
    if (t == 255) rowptr[NN] = part[255];
}

// ---------------- CSR build: scatter edge sources ----------------
__global__ void aml_scatter2_k(const int* __restrict__ ei, int* __restrict__ cursor,
                               int* __restrict__ eid) {
    int e = blockIdx.x * 256 + threadIdx.x;
    if (e >= EE) return;
    int slot = atomicAdd(&cursor[ei[EE + e]], 1);
    eid[slot] = ei[e];
}

// ---------------- gather-mean + concat: ac[i] = [mean_{j->i} x_j | x_i] ----------------
__global__ void aml_gather_k(const float* __restrict__ x, const int* __restrict__ rowptr,
                             const int* __restrict__ eid, float* __restrict__ ac) {
    int node = blockIdx.x * 4 + (threadIdx.x >> 6);
    int lane = threadIdx.x & 63;
    int p0 = rowptr[node], p1 = rowptr[node + 1];
    float ax = 0.f, ay = 0.f;
    int j = p0;
    for (; j + 1 < p1; j += 2) {
        int s0 = eid[j], s1 = eid[j + 1];
        float2 v0 = *(const float2*)(x + (size_t)s0 * DIN + lane * 2);
        float2 v1 = *(const float2*)(x + (size_t)s1 * DIN + lane * 2);
        ax += v0.x + v1.x; ay += v0.y + v1.y;
    }
    if (j < p1) {
        float2 v = *(const float2*)(x + (size_t)eid[j] * DIN + lane * 2);
        ax += v.x; ay += v.y;
    }
    float inv = 1.0f / fmaxf((float)(p1 - p0), 1.0f);
    float2 xr = *(const float2*)(x + (size_t)node * DIN + lane * 2);
    float2 mv = { ax * inv, ay * inv };
    *(float2*)(ac + (size_t)node * DD + lane * 2) = mv;
    *(float2*)(ac + (size_t)node * DD + DIN + lane * 2) = xr;
}

// ---------------- build concat weight [lin_l | lin_r] ----------------
__global__ void aml_wcat_k(const float* __restrict__ wl, const float* __restrict__ wr,
                           float* __restrict__ wcat) {
    int d = blockIdx.x;
    int k = threadIdx.x;
    wcat[(size_t)d * DD + k] = (k < DIN) ? wl[(size_t)d * DIN + k]
                                         : wr[(size_t)d * DIN + (k - DIN)];
}

// ---------------- MFMA GEMM: C[N x M] = A[N x 256] * W[M x 256]^T + bias ----------------
template <int RELU>
__global__ __launch_bounds__(256)
void aml_gemm_k(const float* __restrict__ A, const float* __restrict__ W,
                const float* __restrict__ bias, float* __restrict__ C, int M) {
    __shared__ __align__(16) unsigned char lds[65536];
    const int t = threadIdx.x;
    const int brow = blockIdx.x * 64;
    const int bcol = blockIdx.y * 64;

    const float* srcA = A + (size_t)brow * 256;
    const float* srcW = W + (size_t)bcol * 256;
    #pragma unroll
    for (int p = 0; p < 8; ++p) {
        int c = t + p * 256;
        int row = c >> 5;
        int colb = (c & 31) * 16;
        int dst = row * 512 + (colb ^ ((row & 7) << 4));
        const float* sA = srcA + row * 256 + (c & 31) * 8;
        const float* sW = srcW + row * 256 + (c & 31) * 8;
        float4 a0 = *(const float4*)sA;
        float4 a1 = *(const float4*)(sA + 4);
        uint4 pa = { pk2(a0.x, a0.y), pk2(a0.z, a0.w), pk2(a1.x, a1.y), pk2(a1.z, a1.w) };
        *(uint4*)(lds + dst) = pa;
        float4 w0 = *(const float4*)sW;
        float4 w1 = *(const float4*)(sW + 4);
        uint4 pw = { pk2(w0.x, w0.y), pk2(w0.z, w0.w), pk2(w1.x, w1.y), pk2(w1.z, w1.w) };
        *(uint4*)(lds + 32768 + dst) = pw;
    }
    __syncthreads();

    const int wave = t >> 6, lane = t & 63;
    const int lrow = lane & 15, lk = lane >> 4;
    const int arow = wave * 16 + lrow;
    f32x4 acc[4] = {};
    #pragma unroll
    for (int ks = 0; ks < 8; ++ks) {
        int kbyte = ks * 64 + lk * 16;
        short8 af = *(const short8*)(lds + arow * 512 + (kbyte ^ ((arow & 7) << 4)));
        #pragma unroll
        for (int ct = 0; ct < 4; ++ct) {
            int wrow = ct * 16 + lrow;
            short8 bf = *(const short8*)(lds + 32768 + wrow * 512 + (kbyte ^ ((wrow & 7) << 4)));
            acc[ct] = __builtin_amdgcn_mfma_f32_16x16x32_bf16(af, bf, acc[ct], 0, 0, 0);
        }
    }

    #pragma unroll
    for (int ct = 0; ct < 4; ++ct) {
        int col = bcol + ct * 16 + lrow;
        float bv = bias[col];
        #pragma unroll
        for (int r = 0; r < 4; ++r) {
            int grow = brow + wave * 16 + lk * 4 + r;
            float v = acc[ct][r] + bv;
            if (RELU) v = fmaxf(v, 0.0f);
            C[(size_t)grow * M + col] = v;
        }
    }
}

// ---------------- BatchNorm stats: coalesced rows, atomic partials ----------------
__global__ void aml_bn_stats_k(const float* __restrict__ h, float* __restrict__ stats) {
    int d = threadIdx.x;
    int r0 = blockIdx.x * 96;
    float s = 0.f, ss = 0.f;
    for (int i = 0; i < 96; ++i) {
        float v = h[(size_t)(r0 + i) * DD + d];
        s += v; ss += v * v;
    }
    atomicAdd(&stats[d], s);
    atomicAdd(&stats[DD + d], ss);
}

__global__ void aml_bn_apply_k(float* __restrict__ h, const float* __restrict__ stats,
                               const float* __restrict__ g, const float* __restrict__ b) {
    int idx = blockIdx.x * 256 + threadIdx.x;
    int d = idx & (DD - 1);
    float mu = stats[d] * (1.0f / NN);
    float var = stats[DD + d] * (1.0f / NN) - mu * mu;
    float v = (h[idx] - mu) * rsqrtf(var + 1e-5f) * g[d] + b[d];
    h[idx] = fmaxf(v, 0.0f);
}

// ---------------- timestep segment offsets ----------------
__global__ void aml_offsets_k(const int* __restrict__ ts, int* __restrict__ offs) {
    int t = threadIdx.x;
    if (t > TT) return;
    int lo = 0, hi = NN;
    while (lo < hi) {
        int mid = (lo + hi) >> 1;
        if (ts[mid] < t) lo = mid + 1; else hi = mid;
    }
    offs[t] = lo;
}

// ---------------- MFMA flash attention over block-diagonal segments ----------------
__global__ __launch_bounds__(256)
void aml_attn_k(const float* __restrict__ qkv, const int* __restrict__ offs,
                float* __restrict__ o) {
    int tb = blockIdx.x, head = blockIdx.y, z = blockIdx.z;
    int start = offs[tb], end = offs[tb + 1];
    int S = end - start;
    if (S <= z * 64) return;
    int t = threadIdx.x, wave = t >> 6, lane = t & 63;
    int lq = lane & 15, lk = lane >> 4;
    int qoff = head * 64;

    __shared__ __align__(16) unsigned char Kl[8192];     // [64k][64d] bf16, swizzled
    __shared__ __align__(16) unsigned char Vt[8192];     // [64d][64k] bf16, swizzled
    __shared__ __align__(16) unsigned char Pl[4][2048];  // per-wave [16q][64k] bf16, swizzled
    __shared__ float Ol[4][16][65];                      // per-wave O scratch f32, padded

    int qi = start + z * 64 + wave * 16 + lq;
    int qic = min(qi, end - 1);
    const float* qp = qkv + (size_t)qic * 768 + qoff + lk * 8;
    short8 qf[2];
    #pragma unroll
    for (int ks = 0; ks < 2; ++ks) {
        float4 a = *(const float4*)(qp + ks * 32);
        float4 b = *(const float4*)(qp + ks * 32 + 4);
        qf[ks] = pack8(a, b, 0.125f);
    }

    float m = -1e30f, l = 0.f;
    f32x4 acc[4] = {};

    int ntile = (S + 63) >> 6;
    for (int tile = 0; tile < ntile; ++tile) {
        int jcnt = S - tile * 64; if (jcnt > 64) jcnt = 64;
        {
            int j = t >> 2, d0 = (t & 3) * 16;
            unsigned char* krow = Kl + j * 128;
            if (j < jcnt) {
                const float* kp = qkv + (size_t)(start + tile * 64 + j) * 768 + 256 + qoff + d0;
                float4 k0 = *(const float4*)kp, k1 = *(const float4*)(kp + 4);
                float4 k2 = *(const float4*)(kp + 8), k3 = *(const float4*)(kp + 12);
                uint4 pc0 = { pk2(k0.x, k0.y), pk2(k0.z, k0.w), pk2(k1.x, k1.y), pk2(k1.z, k1.w) };
                uint4 pc1 = { pk2(k2.x, k2.y), pk2(k2.z, k2.w), pk2(k3.x, k3.y), pk2(k3.z, k3.w) };
                *(uint4*)(krow + ((d0 * 2) ^ ((j & 7) << 4))) = pc0;
                *(uint4*)(krow + ((d0 * 2 + 16) ^ ((j & 7) << 4))) = pc1;
                const float* vp = kp + 256;
                float4 v0 = *(const float4*)vp, v1 = *(const float4*)(vp + 4);
                float4 v2 = *(const float4*)(vp + 8), v3 = *(const float4*)(vp + 12);
                float vv[16] = { v0.x, v0.y, v0.z, v0.w, v1.x, v1.y, v1.z, v1.w,
                                 v2.x, v2.y, v2.z, v2.w, v3.x, v3.y, v3.z, v3.w };
                #pragma unroll
                for (int i = 0; i < 16; ++i) {
                    int d = d0 + i;
                    *(unsigned short*)(Vt + d * 128 + ((j * 2) ^ ((d & 7) << 4))) = f2bf(vv[i]);
                }
            } else {
                uint4 zz = { 0, 0, 0, 0 };
                *(uint4*)(krow + ((d0 * 2) ^ ((j & 7) << 4))) = zz;
                *(uint4*)(krow + ((d0 * 2 + 16) ^ ((j & 7) << 4))) = zz;
                #pragma unroll
                for (int i = 0; i < 16; ++i) {
                    int d = d0 + i;
                    *(unsigned short*)(Vt + d * 128 + ((j * 2) ^ ((d & 7) << 4))) = 0;
                }
            }
        }
        __syncthreads();

        f32x4 sv[4];
        #pragma unroll
        for (int kt = 0; kt < 4; ++kt) {
            int kr = kt * 16 + lq;
            f32x4 s = {};
            #pragma unroll
            for (int ks = 0; ks < 2; ++ks) {
                short8 kf = *(const short8*)(Kl + kr * 128 + ((ks * 64 + lk * 16) ^ ((kr & 7) << 4)));
                s = __builtin_amdgcn_mfma_f32_16x16x32_bf16(kf, qf[ks], s, 0, 0, 0);
            }
            sv[kt] = s;
        }
        float pm = -1e30f;
        #pragma unroll
        for (int kt = 0; kt < 4; ++kt) {
            #pragma unroll
            for (int r = 0; r < 4; ++r) {
                int kk = tile * 64 + kt * 16 + lk * 4 + r;
                float s = (kk < S) ? sv[kt][r] : -1e30f;
                sv[kt][r] = s;
                pm = fmaxf(pm, s);
            }
        }
        pm = fmaxf(pm, __shfl_xor(pm, 16));
        pm = fmaxf(pm, __shfl_xor(pm, 32));
        float mn = fmaxf(m, pm);
        float corr = __expf(m - mn);
        m = mn;
        float ps = 0.f;
        #pragma unroll
        for (int kt = 0; kt < 4; ++kt) {
            #pragma unroll
            for (int r = 0; r < 4; ++r) {
                float p = __expf(sv[kt][r] - mn);
                sv[kt][r] = p;
                ps += p;
            }
            uint2 w = { pk2(sv[kt][0], sv[kt][1]), pk2(sv[kt][2], sv[kt][3]) };
            *(uint2*)(Pl[wave] + lq * 128 + ((kt * 32 + lk * 8) ^ ((lq & 7) << 4))) = w;
        }
        ps += __shfl_xor(ps, 16);
        ps += __shfl_xor(ps, 32);
        l = l * corr + ps;
        #pragma unroll
        for (int dt = 0; dt < 4; ++dt) {
            #pragma unroll
            for (int r = 0; r < 4; ++r) acc[dt][r] *= corr;
        }
        #pragma unroll
        for (int ks = 0; ks < 2; ++ks) {
            short8 pf = *(const short8*)(Pl[wave] + lq * 128 + ((ks * 64 + lk * 16) ^ ((lq & 7) << 4)));
            #pragma unroll
            for (int dt = 0; dt < 4; ++dt) {
                int dr = dt * 16 + lq;
                short8 vf = *(const short8*)(Vt + dr * 128 + ((ks * 64 + lk * 16) ^ ((dr & 7) << 4)));
                acc[dt] = __builtin_amdgcn_mfma_f32_16x16x32_bf16(vf, pf, acc[dt], 0, 0, 0);
            }
        }
        __syncthreads();
    }

    float linv = 1.0f / l;
    #pragma unroll
    for (int dt = 0; dt < 4; ++dt) {
        #pragma unroll
        for (int r = 0; r < 4; ++r)
            Ol[wave][lq][dt * 16 + lk * 4 + r] = acc[dt][r] * linv;
    }
    int q2 = lane >> 2, c2 = lane & 3;
    int qg = start + z * 64 + wave * 16 + q2;
    if (qg < end) {
        float* op = o + (size_t)qg * DD + qoff + c2 * 16;
        const float* sp = &Ol[wave][q2][c2 * 16];
        #pragma unroll
        for (int i = 0; i < 4; ++i) ((float4*)op)[i] = *(const float4*)(sp + i * 4);
    }
}

// ---------------- residual + LayerNorm: wave per row ----------------
__global__ void aml_ln_k(float* __restrict__ h, const float* __restrict__ r,
                         const float* __restrict__ g, const float* __restrict__ b) {
    int row = blockIdx.x * 4 + (threadIdx.x >> 6);
    int lane = threadIdx.x & 63;
    float* hp = h + (size_t)row * DD + lane * 4;
    float4 v = *(const float4*)hp;
    float4 rv = *(const float4*)(r + (size_t)row * DD + lane * 4);
    v.x += rv.x; v.y += rv.y; v.z += rv.z; v.w += rv.w;
    float s = v.x + v.y + v.z + v.w;
    float ss = v.x * v.x + v.y * v.y + v.z * v.z + v.w * v.w;
    #pragma unroll
    for (int off = 32; off; off >>= 1) {
        s += __shfl_xor(s, off);
        ss += __shfl_xor(ss, off);
    }
    float mu = s * (1.0f / DD);
    float var = ss * (1.0f / DD) - mu * mu;
    float inv = rsqrtf(var + 1e-5f);
    float4 gv = *(const float4*)(g + lane * 4);
    float4 bv = *(const float4*)(b + lane * 4);
    v.x = (v.x - mu) * inv * gv.x + bv.x;
    v.y = (v.y - mu) * inv * gv.y + bv.y;
    v.z = (v.z - mu) * inv * gv.z + bv.z;
    v.w = (v.w - mu) * inv * gv.w + bv.w;
    *(float4*)hp = v;
}

// ---------------- classifier: wave per row ----------------
__global__ void aml_cls_k(const float* __restrict__ h, const float* __restrict__ w,
                          const float* __restrict__ b, float* __restrict__ out) {
    int row = blockIdx.x * 4 + (threadIdx.x >> 6);
    int lane = threadIdx.x & 63;
    float4 v = *(const float4*)(h + (size_t)row * DD + lane * 4);
    float4 w0 = *(const float4*)(w + lane * 4);
    float4 w1 = *(const float4*)(w + DD + lane * 4);
    float a0 = v.x * w0.x + v.y * w0.y + v.z * w0.z + v.w * w0.w;
    float a1 = v.x * w1.x + v.y * w1.y + v.z * w1.z + v.w * w1.w;
    #pragma unroll
    for (int off = 32; off; off >>= 1) {
        a0 += __shfl_xor(a0, off);
        a1 += __shfl_xor(a1, off);
    }
    if (lane == 0) {
        out[row * 2]     = a0 + b[0];
        out[row * 2 + 1] = a1 + b[1];
    }
}

extern "C" void kernel_launch(void* const* d_in, const int* in_sizes, int n_in,
                              void* d_out, int out_size, void* d_ws, size_t ws_size,
                              hipStream_t stream) {
    const float* x       = (const float*)d_in[0];
    const int*   ei      = (const int*)d_in[1];
    const int*   ts      = (const int*)d_in[2];
    const float* lin_l_w = (const float*)d_in[3];
    const float* lin_l_b = (const float*)d_in[4];
    const float* lin_r_w = (const float*)d_in[5];
    const float* bn_g    = (const float*)d_in[6];
    const float* bn_b    = (const float*)d_in[7];
    const float* inp_w   = (const float*)d_in[8];
    const float* inp_b   = (const float*)d_in[9];
    const float* out_w   = (const float*)d_in[10];
    const float* out_b   = (const float*)d_in[11];
    const float* ff1_w   = (const float*)d_in[12];
    const float* ff1_b   = (const float*)d_in[13];
    const float* ff2_w   = (const float*)d_in[14];
    const float* ff2_b   = (const float*)d_in[15];
    const float* ln1_g   = (const float*)d_in[16];
    const float* ln1_b   = (const float*)d_in[17];
    const float* ln2_g   = (const float*)d_in[18];
    const float* ln2_b   = (const float*)d_in[19];
    const float* cls_w   = (const float*)d_in[20];
    const float* cls_b   = (const float*)d_in[21];

    float* ws     = (float*)d_ws;
    float* stats  = ws;                        // 512 f32 (zeroed)
    int*   deg    = (int*)(stats + 512);       // 6144 (zeroed)
    int*   rowptr = deg + NN;                  // 6145
    int*   cursor = rowptr + NN + 1;           // 6144
    int*   eid    = cursor + NN;               // 98304
    int*   offs   = eid + EE;                  // 64
    float* h      = (float*)(offs + 64);       // N*256
    float* qkv    = h + (size_t)NN * DD;       // N*768
    float* t1     = qkv + (size_t)NN * 768;    // N*256
    float* t2     = t1 + (size_t)NN * DD;      // N*256
    float* ac     = qkv;                       // alias (consumed before qkv written)
    float* wcat   = t1;                        // alias

    // zero stats + deg in one shot (adjacent)
    hipMemsetAsync(stats, 0, 512 * sizeof(float) + NN * sizeof(int), stream);

    aml_hist_k<<<EE / 256, 256, 0, stream>>>(ei, deg);
    aml_scan_k<<<1, 256, 0, stream>>>(deg, rowptr, cursor);
    aml_scatter2_k<<<EE / 256, 256, 0, stream>>>(ei, cursor, eid);
    aml_gather_k<<<NN / 4, 256, 0, stream>>>(x, rowptr, eid, ac);
    aml_wcat_k<<<DD, 256, 0, stream>>>(lin_l_w, lin_r_w, wcat);
    aml_offsets_k<<<1, 64, 0, stream>>>(ts, offs);
    aml_gemm_k<0><<<dim3(NN / 64, 4), 256, 0, stream>>>(ac, wcat, lin_l_b, h, DD);
    aml_bn_stats_k<<<64, 256, 0, stream>>>(h, stats);
    aml_bn_apply_k<<<(NN * DD) / 256, 256, 0, stream>>>(h, stats, bn_g, bn_b);

    for (int l = 0; l < 2; ++l) {
        aml_gemm_k<0><<<dim3(NN / 64, 12), 256, 0, stream>>>(h, inp_w + (size_t)l * 768 * DD,
                                                             inp_b + (size_t)l * 768, qkv, 768);
        aml_attn_k<<<dim3(TT, NH, ATTN_Z), 256, 0, stream>>>(qkv, offs, t1);
        aml_gemm_k<0><<<dim3(NN / 64, 4), 256, 0, stream>>>(t1, out_w + (size_t)l * DD * DD,
                                                            out_b + (size_t)l * DD, t2, DD);
        aml_ln_k<<<NN / 4, 256, 0, stream>>>(h, t2, ln1_g + (size_t)l * DD, ln1_b + (size_t)l * DD);
        aml_gemm_k<1><<<dim3(NN / 64, 4), 256, 0, stream>>>(h, ff1_w + (size_t)l * DD * DD,
                                                            ff1_b + (size_t)l * DD, t1, DD);
        aml_gemm_k<0><<<dim3(NN / 64, 4), 256, 0, stream>>>(t1, ff2_w + (size_t)l * DD * DD,
                                                            ff2_b + (size_t)l * DD, t2, DD);
        aml_ln_k<<<NN / 4, 256, 0, stream>>>(h, t2, ln2_g + (size_t)l * DD, ln2_b + (size_t)l * DD);
    }

    aml_cls_k<<<NN / 4, 256, 0, stream>>>(h, cls_w, cls_b, (float*)d_out);
}